// Round 7
// baseline (379.281 us; speedup 1.0000x reference)
//
#include <hip/hip_runtime.h>
#include <stdint.h>

typedef __bf16 bf16;
typedef bf16 bf16x4 __attribute__((ext_vector_type(4)));
typedef bf16 bf16x8 __attribute__((ext_vector_type(8)));
typedef float f32x4 __attribute__((ext_vector_type(4)));

#define N_NODES 131072
#define D_IN    128
#define KEXP    1024
#define H_DIM   512
#define NGRP    4
#define NPG     32768   // N_NODES / NGRP
#define F_SEG   8192
#define G_SEG   32
#define C_OUT   16

// async global->LDS DMA, 16B per lane; LDS dest = wave-uniform base + lane*16
typedef const __attribute__((address_space(1))) void* gas_t;
typedef __attribute__((address_space(3))) void* las_t;
__device__ __forceinline__ void cp16_async(const bf16* g, bf16* l) {
    __builtin_amdgcn_global_load_lds((gas_t)g, (las_t)l, 16, 0, 0);
}

// ---------------------------------------------------------------------------
// One-time weight cast + swizzle into MFMA-fragment order (16x16x32 bf16).
// B-frag: lane (quad=lane>>4, ln=lane&15) holds B[k=quad*8+j][n=ln].
// (The same physical layout serves as A-frag with rows=ln, k=quad*8+j.)
//
// W1F[g][kc(32)][f=ks*2+kt (8)][lane(64)][j(8)]
//     = W1[g][d = ks*32 + quad*8 + j][k' = kc*32 + kt*16 + ln]
// W2F[g][n0t2(2)][kc(32)][f(16)][lane][j]
//     = W2[g][k = kc*32 + quad*8 + j][n = n0t2*256 + f*16 + ln]
// ---------------------------------------------------------------------------
__global__ void convert_weights(const float* __restrict__ W1,
                                const float* __restrict__ W2,
                                bf16* __restrict__ W1F,
                                bf16* __restrict__ W2F)
{
    int t = blockIdx.x * 256 + threadIdx.x;
    if (t < 65536) {
        int slot = t & 63, f = (t >> 6) & 7, kc = (t >> 9) & 31, g = t >> 14;
        int ks = f >> 1, kt = f & 1, quad = slot >> 4, ln = slot & 15;
        int k = kc * 32 + kt * 16 + ln;
        const float* src = W1 + ((size_t)(g * 128 + ks * 32 + quad * 8)) * 1024 + k;
        bf16x8 v;
        #pragma unroll
        for (int j = 0; j < 8; ++j) v[j] = (bf16)src[(size_t)j * 1024];
        *(bf16x8*)(W1F + (size_t)t * 8) = v;
    } else {
        int u = t - 65536;
        if (u < 262144) {
            int slot = u & 63, f = (u >> 6) & 15, kc = (u >> 10) & 31;
            int n0t2 = (u >> 15) & 1, g = u >> 16;
            int quad = slot >> 4, ln = slot & 15;
            int k = kc * 32 + quad * 8;
            int n = n0t2 * 256 + f * 16 + ln;
            const float* src = W2 + ((size_t)(g * 1024 + k)) * 512 + n;
            bf16x8 v;
            #pragma unroll
            for (int j = 0; j < 8; ++j) v[j] = (bf16)src[(size_t)j * 512];
            *(bf16x8*)(W2F + (size_t)u * 8) = v;
        }
    }
}

// ---------------------------------------------------------------------------
// Fused gather + GEMM1(relu) + GEMM2 + scatter.  512 threads (8 waves).
// Round-15: FINE-PHASE schedule (m201/m218 template) + stage1 dedup.
// Ledger: R0/R1/R2/R4/R5/R6 — six structures, all 236-264us, MfmaUtil
// 35-38% = the coarse-2-phase family ceiling (858 TF ~= m97's ~900).
// Escape per measured regime-gate (m233/m196/m218): small MFMA clusters,
// reads-issued-BEFORE-barrier, lgkmcnt(0) after barrier, setprio around
// MFMA, loads never drained mid-pipeline.
//  * Block M128 x N512 (full H): stage1 computed ONCE -> total work
//    206 -> 172 GF (-17%).  1024 blocks, 1 block/CU, 4 generations.
//  * 8 waves: stage1 wave w does rowfrags {w&3, (w&3)+4} x kt2 {2(w>>2),
//    2(w>>2)+1} (16 MFMA/kc64); stage2 wave (mg=w&1, ng=w>>1) does rows
//    mg*64..+64 x cols ng*128..+128 (64 MFMA/kc64), acc2 = 4x8 f32x4.
//  * Per kc64 period, 5 phases x 16 MFMA:
//      Ph1: bba issue | W1(j+1) DMA | w1f ds_reads | BAR | lgkm0 | S1 | BAR
//      Ph2: pack->sHw | a2(ks2=0,mt01) | BAR | lgkm0 | S2 bba mt01 | BAR
//      Ph3: bbb issue | a2(ks2=0,mt23) | BAR | lgkm0 | S2 bba mt23 | BAR
//      Ph4: a2(ks2=1,mt01) | BAR | lgkm0 | S2 bbb mt01 | BAR
//      Ph5: a2(ks2=1,mt23) | vmcnt(0) seal | BAR | lgkm0 | S2 bbb mt23 | BAR
//    vmcnt(0) only at Ph5 (DMA is ~4 phases old -> free); bb waits are
//    compiler-scoreboarded register loads.
// Hazards: sH dbuf — writes(j,Ph2) vs reads(j+1,Ph2..5): >=2 barriers.
//   sW1 dbuf — DMA(j+1,Ph1) vs reads(j-1,Ph1): sealed periods ago.
//   Prologue: vmcnt(2) seals chunk0; vmcnt(0)+barrier after stage1(0)
//   seals chunk1 before the loop's pre-barrier reads.
// LDS: sW1 2x16K + sH 2x16K + sB1 4K = 68 KB.
// ---------------------------------------------------------------------------
__global__ __launch_bounds__(512, 2)
void mlp_kernel(const float* __restrict__ x,
                const int*   __restrict__ gidx,
                const bf16*  __restrict__ W1F,
                const float* __restrict__ b1,
                const bf16*  __restrict__ W2F,
                const float* __restrict__ b2,
                bf16*        __restrict__ NF)
{
    __shared__ __align__(16) bf16 sW1[2][8192]; // chunk: [kc2(2)][f(8)][lane][8]
    __shared__ __align__(16) bf16 sH[2][8192];  // [fm(8)][ks2(2)][lane][8]
    __shared__ __align__(16) float sB1[1024];   // this group's b1 row

    const int tid  = threadIdx.x;
    const int bid  = blockIdx.x;
    const int g    = bid >> 8;
    const int m0   = (bid & 255) * 128;

    const int wave = tid >> 6;
    const int lane = tid & 63;
    const int quad = lane >> 4;
    const int ln   = lane & 15;

    // stage-1 assignment
    const int rfA  = wave & 3;
    const int rfB  = rfA + 4;
    const int ktp  = (wave >> 2) * 2;      // kt2 pair {ktp, ktp+1}
    const int fbase = (wave >> 2) * 8;     // w1f frag base for this kt2 pair
    // stage-2 assignment
    const int mg   = wave & 1;             // rows mg*64 .. +64
    const int ng   = wave >> 1;            // cols ng*128 .. +128

    const int*  gI  = gidx + g * NPG + m0;
    const bf16* W1g = W1F + (size_t)g * 131072;   // [chunk16][8192]
    // W2 pointer with ng's column offset folded in; [kc32][8192] stride
    const bf16* W2g2 = W2F + ((size_t)(g * 2 + (ng >> 1))) * 262144 + (ng & 1) * 4096;

    // ---- gather x B-frags into registers (2 rowfrags, reused all chunks) ----
    bf16x8 xf[2][4];
    #pragma unroll
    for (int r = 0; r < 2; ++r) {
        int rf   = r ? rfB : rfA;
        int node = gI[rf * 16 + ln];
        #pragma unroll
        for (int ks = 0; ks < 4; ++ks) {
            const float* src = x + (size_t)node * D_IN + ks * 32 + quad * 8;
            float4 a = *(const float4*)src;
            float4 b = *(const float4*)(src + 4);
            bf16x8 v;
            v[0] = (bf16)a.x; v[1] = (bf16)a.y; v[2] = (bf16)a.z; v[3] = (bf16)a.w;
            v[4] = (bf16)b.x; v[5] = (bf16)b.y; v[6] = (bf16)b.z; v[7] = (bf16)b.w;
            xf[r][ks] = v;
        }
    }

    // stage bias row to LDS (keeps the K-loop free of stray scalar vmem)
    *(float2*)(sB1 + tid * 2) = *(const float2*)(b1 + g * KEXP + tid * 2);

    f32x4 acc2[4][8];   // [mt: rows mg*64+mt*16][nt: cols ng*128+nt*16]
    #pragma unroll
    for (int a = 0; a < 4; ++a)
        #pragma unroll
        for (int b = 0; b < 8; ++b)
            acc2[a][b] = (f32x4){0.f, 0.f, 0.f, 0.f};

    // pack: acc1 (+bias, relu) -> sH[buf], A-frag order
    auto do_pack = [&](int j, bf16* hdst, const f32x4 (&acc1)[2][2]) {
        #pragma unroll
        for (int r = 0; r < 2; ++r) {
            int rf = r ? rfB : rfA;
            #pragma unroll
            for (int kt = 0; kt < 2; ++kt) {
                int kt2 = ktp + kt;
                float4 bv = *(const float4*)(sB1 + j * 64 + kt2 * 16 + quad * 4);
                float bvr[4] = {bv.x, bv.y, bv.z, bv.w};
                int ks2 = kt2 >> 1;
                int qa  = (kt2 & 1) * 2 + (quad >> 1);
                int j0  = (quad & 1) * 4;
                bf16x4 pk;
                #pragma unroll
                for (int reg = 0; reg < 4; ++reg)
                    pk[reg] = (bf16)fmaxf(acc1[r][kt][reg] + bvr[reg], 0.f);
                *(bf16x4*)(hdst + ((rf * 2 + ks2) * 64 + qa * 16 + ln) * 8 + j0) = pk;
            }
        }
    };

    // one stage-2 row: acc[nt] += a2 x bb[nt]
    auto s2row = [&](f32x4 (&acc)[8], bf16x8 a2v, const bf16x8 (&bb)[8]) {
        #pragma unroll
        for (int nt = 0; nt < 8; ++nt)
            acc[nt] = __builtin_amdgcn_mfma_f32_16x16x32_bf16(a2v, bb[nt], acc[nt], 0, 0, 0);
    };

    __syncthreads();   // publish sB1; clean vmem queue before DMA counting

    // ---- preloop: DMA chunk0 -> sW1[0], chunk1 -> sW1[1] (2 segs/wave) ----
    #pragma unroll
    for (int r = 0; r < 2; ++r) {
        int c = r * 8 + wave;
        cp16_async(W1g + c * 512 + lane * 8, sW1[0] + c * 512);
    }
    #pragma unroll
    for (int r = 0; r < 2; ++r) {
        int c = r * 8 + wave;
        cp16_async(W1g + 8192 + c * 512 + lane * 8, sW1[1] + c * 512);
    }
    asm volatile("s_waitcnt vmcnt(2)" ::: "memory");  // chunk0 landed
    __builtin_amdgcn_s_barrier();                      // all waves' chunk0 visible

    // ---- stage1(0) (unphased) ----
    {
        bf16x8 w1f[8];
        #pragma unroll
        for (int f = 0; f < 8; ++f)
            w1f[f] = *(const bf16x8*)(sW1[0] + ((fbase + f) * 64 + lane) * 8);
        asm volatile("s_waitcnt lgkmcnt(0)" ::: "memory");
        __builtin_amdgcn_sched_barrier(0);
        f32x4 acc1[2][2];
        #pragma unroll
        for (int a = 0; a < 2; ++a)
            #pragma unroll
            for (int b = 0; b < 2; ++b)
                acc1[a][b] = (f32x4){0.f, 0.f, 0.f, 0.f};
        #pragma unroll
        for (int ks = 0; ks < 4; ++ks)
            #pragma unroll
            for (int kt = 0; kt < 2; ++kt)
                #pragma unroll
                for (int r = 0; r < 2; ++r)
                    acc1[r][kt] = __builtin_amdgcn_mfma_f32_16x16x32_bf16(
                        w1f[ks * 2 + kt], xf[r][ks], acc1[r][kt], 0, 0, 0);
        do_pack(0, sH[0], acc1);
    }
    asm volatile("s_waitcnt vmcnt(0)" ::: "memory");  // seal chunk1 DMA
    __builtin_amdgcn_s_barrier();                      // publish sH[0] + chunk1

    #pragma unroll 1
    for (int j = 1; j < 16; ++j) {
        const int jm = j - 1;
        const bf16* w1buf = sW1[j & 1];
        bf16*       sHw   = sH[j & 1];
        const bf16* sHr   = sH[jm & 1];
        const bf16* w2a   = W2g2 + (size_t)(2 * jm) * 8192;   // ks2=0
        const bf16* w2b   = w2a + 8192;                        // ks2=1

        // ================= Ph1: S1(j) =================
        bf16x8 bba[8];
        #pragma unroll
        for (int nt = 0; nt < 8; ++nt)
            bba[nt] = *(const bf16x8*)(w2a + nt * 512 + lane * 8);
        {   // W1(j+1) DMA (after bba issue: bba waits stay counted, DMA stays in flight)
            int nj = (j + 1) & 15;                  // j=15: harmless refetch
            const bf16* src = W1g + (size_t)nj * 8192;
            bf16* dst = sW1[(j + 1) & 1];
            #pragma unroll
            for (int r = 0; r < 2; ++r) {
                int c = r * 8 + wave;
                cp16_async(src + c * 512 + lane * 8, dst + c * 512);
            }
        }
        bf16x8 w1f[8];
        #pragma unroll
        for (int f = 0; f < 8; ++f)
            w1f[f] = *(const bf16x8*)(w1buf + ((fbase + f) * 64 + lane) * 8);
        __builtin_amdgcn_s_barrier();
        asm volatile("s_waitcnt lgkmcnt(0)" ::: "memory");
        __builtin_amdgcn_sched_barrier(0);
        __builtin_amdgcn_s_setprio(1);
        f32x4 acc1[2][2];
        #pragma unroll
        for (int a = 0; a < 2; ++a)
            #pragma unroll
            for (int b = 0; b < 2; ++b)
                acc1[a][b] = (f32x4){0.f, 0.f, 0.f, 0.f};
        #pragma unroll
        for (int ks = 0; ks < 4; ++ks)
            #pragma unroll
            for (int kt = 0; kt < 2; ++kt)
                #pragma unroll
                for (int r = 0; r < 2; ++r)
                    acc1[r][kt] = __builtin_amdgcn_mfma_f32_16x16x32_bf16(
                        w1f[ks * 2 + kt], xf[r][ks], acc1[r][kt], 0, 0, 0);
        __builtin_amdgcn_s_setprio(0);
        __builtin_amdgcn_s_barrier();

        // ================= Ph2: pack + S2(jm, ks2=0, mt01) =================
        do_pack(j, sHw, acc1);
        bf16x8 a00 = *(const bf16x8*)(sHr + (((mg * 4 + 0) * 2 + 0) * 64 + lane) * 8);
        bf16x8 a01 = *(const bf16x8*)(sHr + (((mg * 4 + 1) * 2 + 0) * 64 + lane) * 8);
        __builtin_amdgcn_s_barrier();
        asm volatile("s_waitcnt lgkmcnt(0)" ::: "memory");
        __builtin_amdgcn_sched_barrier(0);
        __builtin_amdgcn_s_setprio(1);
        s2row(acc2[0], a00, bba);
        s2row(acc2[1], a01, bba);
        __builtin_amdgcn_s_setprio(0);
        __builtin_amdgcn_s_barrier();

        // ================= Ph3: S2(jm, ks2=0, mt23) =================
        bf16x8 bbb[8];
        #pragma unroll
        for (int nt = 0; nt < 8; ++nt)
            bbb[nt] = *(const bf16x8*)(w2b + nt * 512 + lane * 8);
        bf16x8 a02 = *(const bf16x8*)(sHr + (((mg * 4 + 2) * 2 + 0) * 64 + lane) * 8);
        bf16x8 a03 = *(const bf16x8*)(sHr + (((mg * 4 + 3) * 2 + 0) * 64 + lane) * 8);
        __builtin_amdgcn_s_barrier();
        asm volatile("s_waitcnt lgkmcnt(0)" ::: "memory");
        __builtin_amdgcn_sched_barrier(0);
        __builtin_amdgcn_s_setprio(1);
        s2row(acc2[2], a02, bba);
        s2row(acc2[3], a03, bba);
        __builtin_amdgcn_s_setprio(0);
        __builtin_amdgcn_s_barrier();

        // ================= Ph4: S2(jm, ks2=1, mt01) =================
        bf16x8 a10 = *(const bf16x8*)(sHr + (((mg * 4 + 0) * 2 + 1) * 64 + lane) * 8);
        bf16x8 a11 = *(const bf16x8*)(sHr + (((mg * 4 + 1) * 2 + 1) * 64 + lane) * 8);
        __builtin_amdgcn_s_barrier();
        asm volatile("s_waitcnt lgkmcnt(0)" ::: "memory");
        __builtin_amdgcn_sched_barrier(0);
        __builtin_amdgcn_s_setprio(1);
        s2row(acc2[0], a10, bbb);
        s2row(acc2[1], a11, bbb);
        __builtin_amdgcn_s_setprio(0);
        __builtin_amdgcn_s_barrier();

        // ================= Ph5: S2(jm, ks2=1, mt23) =================
        bf16x8 a12 = *(const bf16x8*)(sHr + (((mg * 4 + 2) * 2 + 1) * 64 + lane) * 8);
        bf16x8 a13 = *(const bf16x8*)(sHr + (((mg * 4 + 3) * 2 + 1) * 64 + lane) * 8);
        asm volatile("s_waitcnt vmcnt(0)" ::: "memory");  // seal W1(j+1) DMA (old -> free)
        __builtin_amdgcn_s_barrier();
        asm volatile("s_waitcnt lgkmcnt(0)" ::: "memory");
        __builtin_amdgcn_sched_barrier(0);
        __builtin_amdgcn_s_setprio(1);
        s2row(acc2[2], a12, bbb);
        s2row(acc2[3], a13, bbb);
        __builtin_amdgcn_s_setprio(0);
        __builtin_amdgcn_s_barrier();
    }

    // ---- tail: stage2(15) ----
    {
        const bf16* sHr = sH[1];
        const bf16* w2a = W2g2 + (size_t)30 * 8192;
        const bf16* w2b = w2a + 8192;
        bf16x8 bba[8], bbb[8];
        #pragma unroll
        for (int nt = 0; nt < 8; ++nt) {
            bba[nt] = *(const bf16x8*)(w2a + nt * 512 + lane * 8);
            bbb[nt] = *(const bf16x8*)(w2b + nt * 512 + lane * 8);
        }
        #pragma unroll
        for (int mt = 0; mt < 4; ++mt) {
            bf16x8 a20 = *(const bf16x8*)(sHr + (((mg * 4 + mt) * 2 + 0) * 64 + lane) * 8);
            bf16x8 a21 = *(const bf16x8*)(sHr + (((mg * 4 + mt) * 2 + 1) * 64 + lane) * 8);
            s2row(acc2[mt], a20, bba);
            s2row(acc2[mt], a21, bbb);
        }
    }

    // ---- epilogue: + b2, scatter rows to NF[node][H] as bf16 ----
    const float* b2g = b2 + g * H_DIM + ng * 128;
    float b2v[8];
    #pragma unroll
    for (int nt = 0; nt < 8; ++nt) b2v[nt] = b2g[nt * 16 + ln];

    #pragma unroll
    for (int mt = 0; mt < 4; ++mt)
        #pragma unroll
        for (int reg = 0; reg < 4; ++reg) {
            int row  = mg * 64 + mt * 16 + quad * 4 + reg;
            int node = gI[row];
            bf16* dst = NF + (size_t)node * H_DIM + ng * 128;
            #pragma unroll
            for (int nt = 0; nt < 8; ++nt)
                dst[nt * 16 + ln] = (bf16)(acc2[mt][nt][reg] + b2v[nt]);
        }
}

// ---------------------------------------------------------------------------
// segment_max over 16 consecutive nodes per fine cluster (sorted arange ids).
// Thread handles one (f, 8-channel group); uint4 loads (16 B/lane).
// ---------------------------------------------------------------------------
__global__ void pool_kernel(const bf16* __restrict__ NF, float* __restrict__ EMB)
{
    int t  = blockIdx.x * 256 + threadIdx.x;    // 524288 total
    int f  = t >> 6;
    int c8 = (t & 63) * 8;
    const uint4* src = (const uint4*)(NF + (size_t)f * 16 * 512 + c8);
    float m[8];
    #pragma unroll
    for (int i = 0; i < 8; ++i) m[i] = -INFINITY;
    #pragma unroll
    for (int r = 0; r < 16; ++r) {
        uint4 v = src[(size_t)r * 64];
        uint32_t w[4] = {v.x, v.y, v.z, v.w};
        #pragma unroll
        for (int i = 0; i < 4; ++i) {
            m[2*i]   = fmaxf(m[2*i],   __uint_as_float(w[i] << 16));
            m[2*i+1] = fmaxf(m[2*i+1], __uint_as_float(w[i] & 0xffff0000u));
        }
    }
    float* dst = EMB + (size_t)f * 512 + c8;
    *(float4*)dst       = make_float4(m[0], m[1], m[2], m[3]);
    *(float4*)(dst + 4) = make_float4(m[4], m[5], m[6], m[7]);
}

// ---------------------------------------------------------------------------
// Per (coarse group, channel) mean / rsqrt(var+eps) over 256 fine rows.
// ---------------------------------------------------------------------------
__global__ void stats_kernel(const float* __restrict__ EMB,
                             float* __restrict__ MEAN,
                             float* __restrict__ RSIG)
{
    int gc = blockIdx.x;
    int ch = blockIdx.y * 128 + threadIdx.x;
    const float* p = EMB + (size_t)gc * 256 * 512 + ch;
    float s = 0.f, ss = 0.f;
    #pragma unroll 4
    for (int r = 0; r < 256; ++r) {
        float v = p[(size_t)r * 512];
        s += v; ss += v * v;
    }
    float mean = s * (1.f / 256.f);
    float var  = ss * (1.f / 256.f) - mean * mean;
    MEAN[gc * 512 + ch] = mean;
    RSIG[gc * 512 + ch] = rsqrtf(var + 1e-5f);
}

// ---------------------------------------------------------------------------
// logits[f][c] = b_out[c] + sum_h (emb[f][h]-mean)*rsig * w_out[h][c]
// ---------------------------------------------------------------------------
__global__ __launch_bounds__(256)
void classifier_kernel(const float* __restrict__ EMB,
                       const float* __restrict__ MEAN,
                       const float* __restrict__ RSIG,
                       const float* __restrict__ w_out,
                       const float* __restrict__ b_out,
                       float* __restrict__ out)
{
    __shared__ float sW[512 * 16];
    __shared__ float sE[16 * 513];   // +1 pad breaks 4-way bank conflict
    int t  = threadIdx.x;
    int f0 = blockIdx.x * 16;
    int gc = f0 >> 8;

    #pragma unroll
    for (int it = 0; it < 8; ++it) {
        int i = (it * 256 + t) * 4;
        *(float4*)(sW + i) = *(const float4*)(w_out + i);
    }
    #pragma unroll
    for (int it = 0; it < 32; ++it) {
        int i  = it * 256 + t;
        int fr = i >> 9;
        int h  = i & 511;
        float v = EMB[(size_t)(f0 + fr) * 512 + h];
        sE[fr * 513 + h] = (v - MEAN[gc * 512 + h]) * RSIG[gc * 512 + h];
    }
    __syncthreads();

    int fr = t >> 4;
    int c  = t & 15;
    float acc = b_out[c];
    #pragma unroll 8
    for (int h = 0; h < 512; ++h)
        acc += sE[fr * 513 + h] * sW[h * 16 + c];
    out[(size_t)(f0 + fr) * 16 + c] = acc;
}

// ---------------------------------------------------------------------------
// Workspace layout (~156.4 MB):
//   W1F 1 MB | W2F 4 MB | NF 134 MB | EMB 16 MB | MEAN 64K | RSIG 64K
// ---------------------------------------------------------------------------
extern "C" void kernel_launch(void* const* d_in, const int* in_sizes, int n_in,
                              void* d_out, int out_size, void* d_ws, size_t ws_size,
                              hipStream_t stream)
{
    const float* x     = (const float*)d_in[0];
    const int*   gidx  = (const int*)d_in[1];
    const float* W1    = (const float*)d_in[4];
    const float* b1    = (const float*)d_in[5];
    const float* W2    = (const float*)d_in[6];
    const float* b2    = (const float*)d_in[7];
    const float* w_out = (const float*)d_in[8];
    const float* b_out = (const float*)d_in[9];
    float* out = (float*)d_out;

    char* w = (char*)d_ws;
    bf16* W1F = (bf16*)w;  w += (size_t)NGRP * KEXP * D_IN * 2;
    bf16* W2F = (bf16*)w;  w += (size_t)NGRP * H_DIM * KEXP * 2;
    bf16* NF  = (bf16*)w;  w += (size_t)N_NODES * H_DIM * 2;
    float* EMB  = (float*)w; w += (size_t)F_SEG * H_DIM * 4;
    float* MEAN = (float*)w; w += (size_t)G_SEG * H_DIM * 4;
    float* RSIG = (float*)w; w += (size_t)G_SEG * H_DIM * 4;

    convert_weights<<<1280, 256, 0, stream>>>(W1, W2, W1F, W2F);
    mlp_kernel<<<1024, 512, 0, stream>>>(x, gidx, W1F, b1, W2F, b2, NF);
    pool_kernel<<<2048, 256, 0, stream>>>(NF, EMB);
    stats_kernel<<<dim3(32, 4), 128, 0, stream>>>(EMB, MEAN, RSIG);
    classifier_kernel<<<512, 256, 0, stream>>>(EMB, MEAN, RSIG, w_out, b_out, out);
}

// Round 8
// 341.149 us; speedup vs baseline: 1.1118x; 1.1118x over previous
//
#include <hip/hip_runtime.h>
#include <stdint.h>

typedef __bf16 bf16;
typedef bf16 bf16x4 __attribute__((ext_vector_type(4)));
typedef bf16 bf16x8 __attribute__((ext_vector_type(8)));
typedef float f32x4 __attribute__((ext_vector_type(4)));

#define N_NODES 131072
#define D_IN    128
#define KEXP    1024
#define H_DIM   512
#define NGRP    4
#define NPG     32768   // N_NODES / NGRP
#define F_SEG   8192
#define G_SEG   32
#define C_OUT   16

// async global->LDS DMA, 16B per lane; LDS dest = wave-uniform base + lane*16
typedef const __attribute__((address_space(1))) void* gas_t;
typedef __attribute__((address_space(3))) void* las_t;
__device__ __forceinline__ void cp16_async(const bf16* g, bf16* l) {
    __builtin_amdgcn_global_load_lds((gas_t)g, (las_t)l, 16, 0, 0);
}

// ---------------------------------------------------------------------------
// One-time weight cast + swizzle into MFMA-fragment order (16x16x32 bf16).
// B-frag: lane (quad=lane>>4, ln=lane&15) holds B[k=quad*8+j][n=ln].
// (The same physical layout serves as A-frag with rows=ln, k=quad*8+j.)
//
// W1F[g][kc(32)][f=ks*2+kt (8)][lane(64)][j(8)]
//     = W1[g][d = ks*32 + quad*8 + j][k' = kc*32 + kt*16 + ln]
// W2F[g][n0t2(2)][kc(32)][f(16)][lane][j]
//     = W2[g][k = kc*32 + quad*8 + j][n = n0t2*256 + f*16 + ln]
// ---------------------------------------------------------------------------
__global__ void convert_weights(const float* __restrict__ W1,
                                const float* __restrict__ W2,
                                bf16* __restrict__ W1F,
                                bf16* __restrict__ W2F)
{
    int t = blockIdx.x * 256 + threadIdx.x;
    if (t < 65536) {
        int slot = t & 63, f = (t >> 6) & 7, kc = (t >> 9) & 31, g = t >> 14;
        int ks = f >> 1, kt = f & 1, quad = slot >> 4, ln = slot & 15;
        int k = kc * 32 + kt * 16 + ln;
        const float* src = W1 + ((size_t)(g * 128 + ks * 32 + quad * 8)) * 1024 + k;
        bf16x8 v;
        #pragma unroll
        for (int j = 0; j < 8; ++j) v[j] = (bf16)src[(size_t)j * 1024];
        *(bf16x8*)(W1F + (size_t)t * 8) = v;
    } else {
        int u = t - 65536;
        if (u < 262144) {
            int slot = u & 63, f = (u >> 6) & 15, kc = (u >> 10) & 31;
            int n0t2 = (u >> 15) & 1, g = u >> 16;
            int quad = slot >> 4, ln = slot & 15;
            int k = kc * 32 + quad * 8;
            int n = n0t2 * 256 + f * 16 + ln;
            const float* src = W2 + ((size_t)(g * 1024 + k)) * 512 + n;
            bf16x8 v;
            #pragma unroll
            for (int j = 0; j < 8; ++j) v[j] = (bf16)src[(size_t)j * 512];
            *(bf16x8*)(W2F + (size_t)u * 8) = v;
        }
    }
}

// ---------------------------------------------------------------------------
// Fused gather + GEMM1(relu) + GEMM2 + scatter. 256 threads (4 waves).
// Round-16: R2's proven pipeline (best measured: 236us, 858 TF) hosting the
// stage-1 dedup that R7 proved is memory-real (FETCH 79->56MB) but hosted in
// a losing 5-phase schedule (694 TF). Ledger:
//   R2  structure: 236us @ 206 GF (stage1 duplicated per n0t2) = 858 TF
//   R7  dedup + 5-phase lockstep: 248us @ 172 GF = 694 TF  (schedule lost)
// This round: block M64 x N512 (FULL H -> stage1 computed once):
//   stage1 = R4's proven shape: wave w owns m-tile w (16 rows): 8 MFMA +
//            pack -> sH[4 fm tiles]  (xf = 4 frags for its own rows)
//   stage2 = R2's proven shape: wave w owns col-quarter ng=w (128 cols):
//            bb[8] global->reg, reads all 4 sH tiles, 32 MFMA/kc
//   pipeline IDENTICAL to R2: one __syncthreads per kc | W1 DMA->LDS dbuf
//   1-ahead | sH dbuf | stage1(j) || stage2(j-1) | setprio around MFMA.
// True work/wave/kc: 40 MFMA vs R2's 48 -> total 206 -> 172 GF (-17%).
// 2048 blocks (512 m-tiles x 4 g), 2 blocks/CU, 4 even generations.
// Hazards (same discipline as R2):
//   sH[j&1] stage1-writes vs stage2(j-2) reads: separated by top barrier.
//   sW1[(j+1)&1] DMA vs stage1(j-1) reads: reads pre-barrier, DMA post.
//   top __syncthreads drains W1(j) DMA (issued a full period ago).
// LDS: sW1 2x8K + sH 2x4K + sB1 4K = 28 KB.
// ---------------------------------------------------------------------------
__global__ __launch_bounds__(256, 2)
void mlp_kernel(const float* __restrict__ x,
                const int*   __restrict__ gidx,
                const bf16*  __restrict__ W1F,
                const float* __restrict__ b1,
                const bf16*  __restrict__ W2F,
                const float* __restrict__ b2,
                bf16*        __restrict__ NF)
{
    __shared__ __align__(16) bf16 sW1[2][4096]; // [f=ks*2+kt (8)][lane][8]
    __shared__ __align__(16) bf16 sH[2][2048];  // A-frag order [fm (4)][lane][8]
    __shared__ __align__(16) float sB1[1024];   // this group's b1 row

    const int tid  = threadIdx.x;
    const int bid  = blockIdx.x;
    const int g    = bid >> 9;
    const int m0   = (bid & 511) * 64;

    const int wave = tid >> 6;     // stage1: m-tile index | stage2: col-quarter
    const int lane = tid & 63;
    const int quad = lane >> 4;
    const int ln   = lane & 15;

    const int*  gI  = gidx + g * NPG + m0;
    const bf16* W1g = W1F + (size_t)g * 131072;   // [kc32][4096]
    // W2 pointer with this wave's 128-col quarter folded in; [kc32][8192] stride
    const bf16* W2g2 = W2F + ((size_t)(g * 2 + (wave >> 1))) * 262144
                     + (wave & 1) * 4096;

    // ---- gather x B-frags into registers (wave's own 16 rows, all 32 kc) ----
    // frag ks: lane holds x[row = wave*16 + ln][ks*32 + quad*8 ..+8)
    bf16x8 xf[4];
    #pragma unroll
    for (int ks = 0; ks < 4; ++ks) {
        int node = gI[wave * 16 + ln];
        const float* src = x + (size_t)node * D_IN + ks * 32 + quad * 8;
        float4 a = *(const float4*)src;
        float4 b = *(const float4*)(src + 4);
        bf16x8 v;
        v[0] = (bf16)a.x; v[1] = (bf16)a.y; v[2] = (bf16)a.z; v[3] = (bf16)a.w;
        v[4] = (bf16)b.x; v[5] = (bf16)b.y; v[6] = (bf16)b.z; v[7] = (bf16)b.w;
        xf[ks] = v;
    }

    // stage whole bias row to LDS (keeps the K-loop free of stray vmem)
    *(float4*)(sB1 + tid * 4) = *(const float4*)(b1 + g * KEXP + tid * 4);

    f32x4 acc2[4][8];   // [mt: rows mt*16][nt: cols wave*128 + nt*16]
    #pragma unroll
    for (int a = 0; a < 4; ++a)
        #pragma unroll
        for (int b = 0; b < 8; ++b)
            acc2[a][b] = (f32x4){0.f, 0.f, 0.f, 0.f};

    // stage1 helper (R4's proven shape): h[16 rows][32 k'] for chunk j,
    // sW1[j&1] -> sH[j&1], wave's own m-tile (fm = wave).
    auto do_stage1 = [&](int j) {
        const bf16* w1buf = sW1[j & 1];
        bf16*       hdst  = sH[j & 1];
        f32x4 acc1[2];
        acc1[0] = (f32x4){0.f, 0.f, 0.f, 0.f};
        acc1[1] = (f32x4){0.f, 0.f, 0.f, 0.f};
        #pragma unroll
        for (int ks = 0; ks < 4; ++ks) {
            #pragma unroll
            for (int kt = 0; kt < 2; ++kt) {
                bf16x8 w1f = *(const bf16x8*)(w1buf + ((ks * 2 + kt) * 64 + lane) * 8);
                acc1[kt] = __builtin_amdgcn_mfma_f32_16x16x32_bf16(
                    w1f, xf[ks], acc1[kt], 0, 0, 0);
            }
        }
        // bias+relu -> sH via b64 stores (4 contiguous k' per lane at fixed m)
        // value: h[m = wave*16+ln][k' = kt*16+quad*4+reg]
        // dest A-frag elem: fm = wave, qa = kt*2+(quad>>1), j0 = (quad&1)*4
        #pragma unroll
        for (int kt = 0; kt < 2; ++kt) {
            float4 bv = *(const float4*)(sB1 + j * 32 + kt * 16 + quad * 4);
            float bvr[4] = {bv.x, bv.y, bv.z, bv.w};
            int qa = kt * 2 + (quad >> 1);
            int j0 = (quad & 1) * 4;
            bf16x4 pk;
            #pragma unroll
            for (int reg = 0; reg < 4; ++reg)
                pk[reg] = (bf16)fmaxf(acc1[kt][reg] + bvr[reg], 0.f);
            *(bf16x4*)(hdst + (wave * 64 + qa * 16 + ln) * 8 + j0) = pk;
        }
    };

    __syncthreads();   // publish sB1; drains all prologue vmem (clean queue)

    // ---- preloop: DMA W1(0), W1(1) -- 2 segments/wave each (8x512 bf16) ----
    #pragma unroll
    for (int r = 0; r < 2; ++r) {
        int c = r * 4 + wave;
        cp16_async(W1g + c * 512 + lane * 8, sW1[0] + c * 512);
    }
    #pragma unroll
    for (int r = 0; r < 2; ++r) {
        int c = r * 4 + wave;
        cp16_async(W1g + 4096 + c * 512 + lane * 8, sW1[1] + c * 512);
    }
    asm volatile("s_waitcnt vmcnt(2)" ::: "memory");  // W1(0) landed; W1(1) in flight
    __builtin_amdgcn_s_barrier();                      // all waves' W1(0) visible

    do_stage1(0);

    #pragma unroll 1
    for (int j = 1; j < 32; ++j) {
        // one barrier per kc: publishes sH(j-1), seals sW1/sH WAR windows,
        // drains W1(j) DMA (issued a full period ago -> near-free wait)
        __syncthreads();

        // ---- bb(j-1): W2 fragments global->regs (consumed after stage1) ----
        bf16x8 bb[8];
        {
            const bf16* w2src = W2g2 + (size_t)(j - 1) * 8192;
            #pragma unroll
            for (int nt = 0; nt < 8; ++nt)
                bb[nt] = *(const bf16x8*)(w2src + nt * 512 + lane * 8);
        }

        // ---- W1(j+1) DMA (target buffer last read pre-barrier) ----
        {
            int nkc = (j + 1) & 31;                  // j=31: harmless refetch
            const bf16* w1src = W1g + (size_t)nkc * 4096;
            bf16* d1 = sW1[(j + 1) & 1];
            #pragma unroll
            for (int r = 0; r < 2; ++r) {
                int c = r * 4 + wave;
                cp16_async(w1src + c * 512 + lane * 8, d1 + c * 512);
            }
        }

        // ---- stage 1 (chunk j): 8 MFMA + pack, hides bb flight ----
        __builtin_amdgcn_s_setprio(1);
        do_stage1(j);

        // ---- stage 2 (chunk j-1): 32 MFMA, A = all 4 sH tiles, B = bb ----
        {
            const bf16* hbuf = sH[(j - 1) & 1];
            #pragma unroll
            for (int mt = 0; mt < 4; ++mt) {
                bf16x8 a2 = *(const bf16x8*)(hbuf + (mt * 64 + lane) * 8);
                #pragma unroll
                for (int nt = 0; nt < 8; ++nt)
                    acc2[mt][nt] = __builtin_amdgcn_mfma_f32_16x16x32_bf16(
                        a2, bb[nt], acc2[mt][nt], 0, 0, 0);
            }
        }
        __builtin_amdgcn_s_setprio(0);
    }

    // ---- tail: stage2(31) ----
    __syncthreads();
    {
        bf16x8 bb[8];
        const bf16* w2src = W2g2 + (size_t)31 * 8192;
        #pragma unroll
        for (int nt = 0; nt < 8; ++nt)
            bb[nt] = *(const bf16x8*)(w2src + nt * 512 + lane * 8);
        const bf16* hbuf = sH[1];
        #pragma unroll
        for (int mt = 0; mt < 4; ++mt) {
            bf16x8 a2 = *(const bf16x8*)(hbuf + (mt * 64 + lane) * 8);
            #pragma unroll
            for (int nt = 0; nt < 8; ++nt)
                acc2[mt][nt] = __builtin_amdgcn_mfma_f32_16x16x32_bf16(
                    a2, bb[nt], acc2[mt][nt], 0, 0, 0);
        }
    }

    // ---- epilogue: + b2, scatter rows to NF[node][H] as bf16 ----
    const float* b2g = b2 + g * H_DIM + wave * 128;
    float b2v[8];
    #pragma unroll
    for (int nt = 0; nt < 8; ++nt) b2v[nt] = b2g[nt * 16 + ln];

    #pragma unroll
    for (int mt = 0; mt < 4; ++mt)
        #pragma unroll
        for (int reg = 0; reg < 4; ++reg) {
            int row  = mt * 16 + quad * 4 + reg;
            int node = gI[row];
            bf16* dst = NF + (size_t)node * H_DIM + wave * 128;
            #pragma unroll
            for (int nt = 0; nt < 8; ++nt)
                dst[nt * 16 + ln] = (bf16)(acc2[mt][nt][reg] + b2v[nt]);
        }
}

// ---------------------------------------------------------------------------
// segment_max over 16 consecutive nodes per fine cluster (sorted arange ids).
// Thread handles one (f, 8-channel group); uint4 loads (16 B/lane).
// ---------------------------------------------------------------------------
__global__ void pool_kernel(const bf16* __restrict__ NF, float* __restrict__ EMB)
{
    int t  = blockIdx.x * 256 + threadIdx.x;    // 524288 total
    int f  = t >> 6;
    int c8 = (t & 63) * 8;
    const uint4* src = (const uint4*)(NF + (size_t)f * 16 * 512 + c8);
    float m[8];
    #pragma unroll
    for (int i = 0; i < 8; ++i) m[i] = -INFINITY;
    #pragma unroll
    for (int r = 0; r < 16; ++r) {
        uint4 v = src[(size_t)r * 64];
        uint32_t w[4] = {v.x, v.y, v.z, v.w};
        #pragma unroll
        for (int i = 0; i < 4; ++i) {
            m[2*i]   = fmaxf(m[2*i],   __uint_as_float(w[i] << 16));
            m[2*i+1] = fmaxf(m[2*i+1], __uint_as_float(w[i] & 0xffff0000u));
        }
    }
    float* dst = EMB + (size_t)f * 512 + c8;
    *(float4*)dst       = make_float4(m[0], m[1], m[2], m[3]);
    *(float4*)(dst + 4) = make_float4(m[4], m[5], m[6], m[7]);
}

// ---------------------------------------------------------------------------
// Per (coarse group, channel) mean / rsqrt(var+eps) over 256 fine rows.
// ---------------------------------------------------------------------------
__global__ void stats_kernel(const float* __restrict__ EMB,
                             float* __restrict__ MEAN,
                             float* __restrict__ RSIG)
{
    int gc = blockIdx.x;
    int ch = blockIdx.y * 128 + threadIdx.x;
    const float* p = EMB + (size_t)gc * 256 * 512 + ch;
    float s = 0.f, ss = 0.f;
    #pragma unroll 4
    for (int r = 0; r < 256; ++r) {
        float v = p[(size_t)r * 512];
        s += v; ss += v * v;
    }
    float mean = s * (1.f / 256.f);
    float var  = ss * (1.f / 256.f) - mean * mean;
    MEAN[gc * 512 + ch] = mean;
    RSIG[gc * 512 + ch] = rsqrtf(var + 1e-5f);
}

// ---------------------------------------------------------------------------
// logits[f][c] = b_out[c] + sum_h (emb[f][h]-mean)*rsig * w_out[h][c]
// ---------------------------------------------------------------------------
__global__ __launch_bounds__(256)
void classifier_kernel(const float* __restrict__ EMB,
                       const float* __restrict__ MEAN,
                       const float* __restrict__ RSIG,
                       const float* __restrict__ w_out,
                       const float* __restrict__ b_out,
                       float* __restrict__ out)
{
    __shared__ float sW[512 * 16];
    __shared__ float sE[16 * 513];   // +1 pad breaks 4-way bank conflict
    int t  = threadIdx.x;
    int f0 = blockIdx.x * 16;
    int gc = f0 >> 8;

    #pragma unroll
    for (int it = 0; it < 8; ++it) {
        int i = (it * 256 + t) * 4;
        *(float4*)(sW + i) = *(const float4*)(w_out + i);
    }
    #pragma unroll
    for (int it = 0; it < 32; ++it) {
        int i  = it * 256 + t;
        int fr = i >> 9;
        int h  = i & 511;
        float v = EMB[(size_t)(f0 + fr) * 512 + h];
        sE[fr * 513 + h] = (v - MEAN[gc * 512 + h]) * RSIG[gc * 512 + h];
    }
    __syncthreads();

    int fr = t >> 4;
    int c  = t & 15;
    float acc = b_out[c];
    #pragma unroll 8
    for (int h = 0; h < 512; ++h)
        acc += sE[fr * 513 + h] * sW[h * 16 + c];
    out[(size_t)(f0 + fr) * 16 + c] = acc;
}

// ---------------------------------------------------------------------------
// Workspace layout (~156.4 MB):
//   W1F 1 MB | W2F 4 MB | NF 134 MB | EMB 16 MB | MEAN 64K | RSIG 64K
// ---------------------------------------------------------------------------
extern "C" void kernel_launch(void* const* d_in, const int* in_sizes, int n_in,
                              void* d_out, int out_size, void* d_ws, size_t ws_size,
                              hipStream_t stream)
{
    const float* x     = (const float*)d_in[0];
    const int*   gidx  = (const int*)d_in[1];
    const float* W1    = (const float*)d_in[4];
    const float* b1    = (const float*)d_in[5];
    const float* W2    = (const float*)d_in[6];
    const float* b2    = (const float*)d_in[7];
    const float* w_out = (const float*)d_in[8];
    const float* b_out = (const float*)d_in[9];
    float* out = (float*)d_out;

    char* w = (char*)d_ws;
    bf16* W1F = (bf16*)w;  w += (size_t)NGRP * KEXP * D_IN * 2;
    bf16* W2F = (bf16*)w;  w += (size_t)NGRP * H_DIM * KEXP * 2;
    bf16* NF  = (bf16*)w;  w += (size_t)N_NODES * H_DIM * 2;
    float* EMB  = (float*)w; w += (size_t)F_SEG * H_DIM * 4;
    float* MEAN = (float*)w; w += (size_t)G_SEG * H_DIM * 4;
    float* RSIG = (float*)w; w += (size_t)G_SEG * H_DIM * 4;

    convert_weights<<<1280, 256, 0, stream>>>(W1, W2, W1F, W2F);
    mlp_kernel<<<2048, 256, 0, stream>>>(x, gidx, W1F, b1, W2F, b2, NF);
    pool_kernel<<<2048, 256, 0, stream>>>(NF, EMB);
    stats_kernel<<<dim3(32, 4), 128, 0, stream>>>(EMB, MEAN, RSIG);
    classifier_kernel<<<512, 256, 0, stream>>>(EMB, MEAN, RSIG, w_out, b_out, out);
}

// Round 9
// 340.105 us; speedup vs baseline: 1.1152x; 1.0031x over previous
//
#include <hip/hip_runtime.h>
#include <stdint.h>

typedef __bf16 bf16;
typedef bf16 bf16x4 __attribute__((ext_vector_type(4)));
typedef bf16 bf16x8 __attribute__((ext_vector_type(8)));
typedef float f32x4 __attribute__((ext_vector_type(4)));

#define N_NODES 131072
#define D_IN    128
#define KEXP    1024
#define H_DIM   512
#define NGRP    4
#define NPG     32768   // N_NODES / NGRP
#define F_SEG   8192
#define G_SEG   32
#define C_OUT   16

// async global->LDS DMA, 16B per lane; LDS dest = wave-uniform base + lane*16
typedef const __attribute__((address_space(1))) void* gas_t;
typedef __attribute__((address_space(3))) void* las_t;
__device__ __forceinline__ void cp16_async(const bf16* g, bf16* l) {
    __builtin_amdgcn_global_load_lds((gas_t)g, (las_t)l, 16, 0, 0);
}

// ---------------------------------------------------------------------------
// One-time weight cast + swizzle into MFMA-fragment order (16x16x32 bf16).
// B-frag: lane (quad=lane>>4, ln=lane&15) holds B[k=quad*8+j][n=ln].
// (The same physical layout serves as A-frag with rows=ln, k=quad*8+j.)
//
// W1F[g][kc(32)][f=ks*2+kt (8)][lane(64)][j(8)]
//     = W1[g][d = ks*32 + quad*8 + j][k' = kc*32 + kt*16 + ln]
// W2F[g][n0t2(2)][kc(32)][f(16)][lane][j]
//     = W2[g][k = kc*32 + quad*8 + j][n = n0t2*256 + f*16 + ln]
// ---------------------------------------------------------------------------
__global__ void convert_weights(const float* __restrict__ W1,
                                const float* __restrict__ W2,
                                bf16* __restrict__ W1F,
                                bf16* __restrict__ W2F)
{
    int t = blockIdx.x * 256 + threadIdx.x;
    if (t < 65536) {
        int slot = t & 63, f = (t >> 6) & 7, kc = (t >> 9) & 31, g = t >> 14;
        int ks = f >> 1, kt = f & 1, quad = slot >> 4, ln = slot & 15;
        int k = kc * 32 + kt * 16 + ln;
        const float* src = W1 + ((size_t)(g * 128 + ks * 32 + quad * 8)) * 1024 + k;
        bf16x8 v;
        #pragma unroll
        for (int j = 0; j < 8; ++j) v[j] = (bf16)src[(size_t)j * 1024];
        *(bf16x8*)(W1F + (size_t)t * 8) = v;
    } else {
        int u = t - 65536;
        if (u < 262144) {
            int slot = u & 63, f = (u >> 6) & 15, kc = (u >> 10) & 31;
            int n0t2 = (u >> 15) & 1, g = u >> 16;
            int quad = slot >> 4, ln = slot & 15;
            int k = kc * 32 + quad * 8;
            int n = n0t2 * 256 + f * 16 + ln;
            const float* src = W2 + ((size_t)(g * 1024 + k)) * 512 + n;
            bf16x8 v;
            #pragma unroll
            for (int j = 0; j < 8; ++j) v[j] = (bf16)src[(size_t)j * 512];
            *(bf16x8*)(W2F + (size_t)u * 8) = v;
        }
    }
}

// ---------------------------------------------------------------------------
// Fused gather + GEMM1(relu) + GEMM2 + scatter.  512 threads (8 waves).
// Round-17: STREAM-DEPTH test. R8 analysis: true regs/wave ~236 (108 VGPR +
// 128 acc) -> 2048/236 = 8 waves/CU = 2/SIMD (matches measured 22%).
// All ~850-TF rounds ran <=2-3 bursty MFMA streams/SIMD; hypothesis: the
// matrix pipe needs >=4 concurrent wave-streams to sustain ubench rate.
// Controlled A/B vs R8: SAME 2048 blocks, SAME M64xN512 tile, SAME
// dataflow/barrier/DMA/LDS/generations — but each R8 wave split in two:
//   stage1: wave w = (rf = w&3, kt = w>>2): 4 MFMA chain + 1 b64 pack-store
//   stage2: wave w = cols w*64..+64: bb[4] global->reg, 16 MFMA
//   acc2[4][4] = 64 regs; target total <=128 -> 16 waves/CU = 4/SIMD
//   (__launch_bounds__(512,4) enforces the register budget).
// Only occupancy & work/wave change -> clean test of the hypothesis.
// LDS: sW1 2x8K + sH 2x4K + sB1 4K = 28 KB (2 blocks/CU -> 56 KB).
// Hazards identical to R8 (one __syncthreads per kc seals everything):
//   sH dbuf write(j) vs stage2(j-2) readers: sealed by top barrier.
//   sW1 dbuf DMA(j+1) vs stage1(j-1) readers: reads pre-barrier.
//   top barrier's vmcnt(0) drains W1(j) DMA (issued a period ago).
// ---------------------------------------------------------------------------
__global__ __launch_bounds__(512, 4)
void mlp_kernel(const float* __restrict__ x,
                const int*   __restrict__ gidx,
                const bf16*  __restrict__ W1F,
                const float* __restrict__ b1,
                const bf16*  __restrict__ W2F,
                const float* __restrict__ b2,
                bf16*        __restrict__ NF)
{
    __shared__ __align__(16) bf16 sW1[2][4096]; // [f=ks*2+kt (8)][lane][8]
    __shared__ __align__(16) bf16 sH[2][2048];  // A-frag order [fm (4)][lane][8]
    __shared__ __align__(16) float sB1[1024];   // this group's b1 row

    const int tid  = threadIdx.x;
    const int bid  = blockIdx.x;
    const int g    = bid >> 9;
    const int m0   = (bid & 511) * 64;

    const int wave = tid >> 6;
    const int lane = tid & 63;
    const int quad = lane >> 4;
    const int ln   = lane & 15;

    const int rf = wave & 3;     // stage1: row-frag (rows rf*16..+16)
    const int kt = wave >> 2;    // stage1: k'-half of the 32-chunk

    const int*  gI  = gidx + g * NPG + m0;
    const bf16* W1g = W1F + (size_t)g * 131072;   // [kc32][4096]
    // stage2: this wave's 64-col slice of H (cols wave*64..+64)
    const bf16* W2g2 = W2F + ((size_t)(g * 2 + (wave >> 2))) * 262144
                     + (size_t)((wave & 3) * 4) * 512;

    // ---- gather x B-frags for this wave's 16 stage-1 rows (all 32 kc) ----
    // frag ks: lane holds x[row = rf*16 + ln][ks*32 + quad*8 ..+8)
    bf16x8 xf[4];
    {
        int node = gI[rf * 16 + ln];
        #pragma unroll
        for (int ks = 0; ks < 4; ++ks) {
            const float* src = x + (size_t)node * D_IN + ks * 32 + quad * 8;
            float4 a = *(const float4*)src;
            float4 b = *(const float4*)(src + 4);
            bf16x8 v;
            v[0] = (bf16)a.x; v[1] = (bf16)a.y; v[2] = (bf16)a.z; v[3] = (bf16)a.w;
            v[4] = (bf16)b.x; v[5] = (bf16)b.y; v[6] = (bf16)b.z; v[7] = (bf16)b.w;
            xf[ks] = v;
        }
    }

    // stage whole bias row to LDS (keeps the K-loop free of stray vmem)
    *(float2*)(sB1 + tid * 2) = *(const float2*)(b1 + g * KEXP + tid * 2);

    f32x4 acc2[4][4];   // [mt: rows mt*16][n: cols wave*64 + n*16]
    #pragma unroll
    for (int a = 0; a < 4; ++a)
        #pragma unroll
        for (int b = 0; b < 4; ++b)
            acc2[a][b] = (f32x4){0.f, 0.f, 0.f, 0.f};

    // stage1: this wave's (rf, kt) quarter of h for chunk j: 4 MFMA + pack
    auto do_stage1 = [&](int j) {
        const bf16* w1buf = sW1[j & 1];
        bf16*       hdst  = sH[j & 1];
        f32x4 acc1 = (f32x4){0.f, 0.f, 0.f, 0.f};
        #pragma unroll
        for (int ks = 0; ks < 4; ++ks) {
            bf16x8 w1f = *(const bf16x8*)(w1buf + ((ks * 2 + kt) * 64 + lane) * 8);
            acc1 = __builtin_amdgcn_mfma_f32_16x16x32_bf16(w1f, xf[ks], acc1, 0, 0, 0);
        }
        // value: h[m = rf*16+ln][k' = kt*16+quad*4+reg]
        // dest A-frag elem: fm = rf, qa = kt*2+(quad>>1), j0 = (quad&1)*4
        float4 bv = *(const float4*)(sB1 + j * 32 + kt * 16 + quad * 4);
        float bvr[4] = {bv.x, bv.y, bv.z, bv.w};
        int qa = kt * 2 + (quad >> 1);
        int j0 = (quad & 1) * 4;
        bf16x4 pk;
        #pragma unroll
        for (int reg = 0; reg < 4; ++reg)
            pk[reg] = (bf16)fmaxf(acc1[reg] + bvr[reg], 0.f);
        *(bf16x4*)(hdst + (rf * 64 + qa * 16 + ln) * 8 + j0) = pk;
    };

    __syncthreads();   // publish sB1; drains all prologue vmem (clean queue)

    // ---- preloop: DMA W1(0), W1(1) -- 1 segment/wave each (8x512 bf16) ----
    cp16_async(W1g + wave * 512 + lane * 8, sW1[0] + wave * 512);
    cp16_async(W1g + 4096 + wave * 512 + lane * 8, sW1[1] + wave * 512);
    asm volatile("s_waitcnt vmcnt(1)" ::: "memory");  // W1(0) landed; W1(1) in flight
    __builtin_amdgcn_s_barrier();                      // all waves' W1(0) visible

    do_stage1(0);

    #pragma unroll 1
    for (int j = 1; j < 32; ++j) {
        // one barrier per kc: publishes sH(j-1), seals sW1/sH WAR windows,
        // drains W1(j) DMA (issued a full period ago -> near-free wait)
        __syncthreads();

        // ---- bb(j-1): W2 fragments global->regs (consumed after stage1) ----
        bf16x8 bb[4];
        {
            const bf16* w2src = W2g2 + (size_t)(j - 1) * 8192;
            #pragma unroll
            for (int n = 0; n < 4; ++n)
                bb[n] = *(const bf16x8*)(w2src + n * 512 + lane * 8);
        }

        // ---- W1(j+1) DMA (target buffer last read pre-barrier) ----
        {
            int nkc = (j + 1) & 31;                  // j=31: harmless refetch
            cp16_async(W1g + (size_t)nkc * 4096 + wave * 512 + lane * 8,
                       sW1[(j + 1) & 1] + wave * 512);
        }

        // ---- stage 1 (chunk j): 4 MFMA + pack, hides bb flight ----
        __builtin_amdgcn_s_setprio(1);
        do_stage1(j);

        // ---- stage 2 (chunk j-1): 16 MFMA, A = 4 sH tiles, B = bb ----
        {
            const bf16* hbuf = sH[(j - 1) & 1];
            #pragma unroll
            for (int mt = 0; mt < 4; ++mt) {
                bf16x8 a2 = *(const bf16x8*)(hbuf + (mt * 64 + lane) * 8);
                #pragma unroll
                for (int n = 0; n < 4; ++n)
                    acc2[mt][n] = __builtin_amdgcn_mfma_f32_16x16x32_bf16(
                        a2, bb[n], acc2[mt][n], 0, 0, 0);
            }
        }
        __builtin_amdgcn_s_setprio(0);
    }

    // ---- tail: stage2(31) ----
    __syncthreads();
    {
        bf16x8 bb[4];
        const bf16* w2src = W2g2 + (size_t)31 * 8192;
        #pragma unroll
        for (int n = 0; n < 4; ++n)
            bb[n] = *(const bf16x8*)(w2src + n * 512 + lane * 8);
        const bf16* hbuf = sH[1];
        #pragma unroll
        for (int mt = 0; mt < 4; ++mt) {
            bf16x8 a2 = *(const bf16x8*)(hbuf + (mt * 64 + lane) * 8);
            #pragma unroll
            for (int n = 0; n < 4; ++n)
                acc2[mt][n] = __builtin_amdgcn_mfma_f32_16x16x32_bf16(
                    a2, bb[n], acc2[mt][n], 0, 0, 0);
        }
    }

    // ---- epilogue: + b2, scatter rows to NF[node][H] as bf16 ----
    const float* b2g = b2 + g * H_DIM + wave * 64;
    float b2v[4];
    #pragma unroll
    for (int n = 0; n < 4; ++n) b2v[n] = b2g[n * 16 + ln];

    #pragma unroll
    for (int mt = 0; mt < 4; ++mt)
        #pragma unroll
        for (int reg = 0; reg < 4; ++reg) {
            int row  = mt * 16 + quad * 4 + reg;
            int node = gI[row];
            bf16* dst = NF + (size_t)node * H_DIM + wave * 64;
            #pragma unroll
            for (int n = 0; n < 4; ++n)
                dst[n * 16 + ln] = (bf16)(acc2[mt][n][reg] + b2v[n]);
        }
}

// ---------------------------------------------------------------------------
// segment_max over 16 consecutive nodes per fine cluster (sorted arange ids).
// Thread handles one (f, 8-channel group); uint4 loads (16 B/lane).
// ---------------------------------------------------------------------------
__global__ void pool_kernel(const bf16* __restrict__ NF, float* __restrict__ EMB)
{
    int t  = blockIdx.x * 256 + threadIdx.x;    // 524288 total
    int f  = t >> 6;
    int c8 = (t & 63) * 8;
    const uint4* src = (const uint4*)(NF + (size_t)f * 16 * 512 + c8);
    float m[8];
    #pragma unroll
    for (int i = 0; i < 8; ++i) m[i] = -INFINITY;
    #pragma unroll
    for (int r = 0; r < 16; ++r) {
        uint4 v = src[(size_t)r * 64];
        uint32_t w[4] = {v.x, v.y, v.z, v.w};
        #pragma unroll
        for (int i = 0; i < 4; ++i) {
            m[2*i]   = fmaxf(m[2*i],   __uint_as_float(w[i] << 16));
            m[2*i+1] = fmaxf(m[2*i+1], __uint_as_float(w[i] & 0xffff0000u));
        }
    }
    float* dst = EMB + (size_t)f * 512 + c8;
    *(float4*)dst       = make_float4(m[0], m[1], m[2], m[3]);
    *(float4*)(dst + 4) = make_float4(m[4], m[5], m[6], m[7]);
}

// ---------------------------------------------------------------------------
// Per (coarse group, channel) mean / rsqrt(var+eps) over 256 fine rows.
// ---------------------------------------------------------------------------
__global__ void stats_kernel(const float* __restrict__ EMB,
                             float* __restrict__ MEAN,
                             float* __restrict__ RSIG)
{
    int gc = blockIdx.x;
    int ch = blockIdx.y * 128 + threadIdx.x;
    const float* p = EMB + (size_t)gc * 256 * 512 + ch;
    float s = 0.f, ss = 0.f;
    #pragma unroll 4
    for (int r = 0; r < 256; ++r) {
        float v = p[(size_t)r * 512];
        s += v; ss += v * v;
    }
    float mean = s * (1.f / 256.f);
    float var  = ss * (1.f / 256.f) - mean * mean;
    MEAN[gc * 512 + ch] = mean;
    RSIG[gc * 512 + ch] = rsqrtf(var + 1e-5f);
}

// ---------------------------------------------------------------------------
// logits[f][c] = b_out[c] + sum_h (emb[f][h]-mean)*rsig * w_out[h][c]
// ---------------------------------------------------------------------------
__global__ __launch_bounds__(256)
void classifier_kernel(const float* __restrict__ EMB,
                       const float* __restrict__ MEAN,
                       const float* __restrict__ RSIG,
                       const float* __restrict__ w_out,
                       const float* __restrict__ b_out,
                       float* __restrict__ out)
{
    __shared__ float sW[512 * 16];
    __shared__ float sE[16 * 513];   // +1 pad breaks 4-way bank conflict
    int t  = threadIdx.x;
    int f0 = blockIdx.x * 16;
    int gc = f0 >> 8;

    #pragma unroll
    for (int it = 0; it < 8; ++it) {
        int i = (it * 256 + t) * 4;
        *(float4*)(sW + i) = *(const float4*)(w_out + i);
    }
    #pragma unroll
    for (int it = 0; it < 32; ++it) {
        int i  = it * 256 + t;
        int fr = i >> 9;
        int h  = i & 511;
        float v = EMB[(size_t)(f0 + fr) * 512 + h];
        sE[fr * 513 + h] = (v - MEAN[gc * 512 + h]) * RSIG[gc * 512 + h];
    }
    __syncthreads();

    int fr = t >> 4;
    int c  = t & 15;
    float acc = b_out[c];
    #pragma unroll 8
    for (int h = 0; h < 512; ++h)
        acc += sE[fr * 513 + h] * sW[h * 16 + c];
    out[(size_t)(f0 + fr) * 16 + c] = acc;
}

// ---------------------------------------------------------------------------
// Workspace layout (~156.4 MB):
//   W1F 1 MB | W2F 4 MB | NF 134 MB | EMB 16 MB | MEAN 64K | RSIG 64K
// ---------------------------------------------------------------------------
extern "C" void kernel_launch(void* const* d_in, const int* in_sizes, int n_in,
                              void* d_out, int out_size, void* d_ws, size_t ws_size,
                              hipStream_t stream)
{
    const float* x     = (const float*)d_in[0];
    const int*   gidx  = (const int*)d_in[1];
    const float* W1    = (const float*)d_in[4];
    const float* b1    = (const float*)d_in[5];
    const float* W2    = (const float*)d_in[6];
    const float* b2    = (const float*)d_in[7];
    const float* w_out = (const float*)d_in[8];
    const float* b_out = (const float*)d_in[9];
    float* out = (float*)d_out;

    char* w = (char*)d_ws;
    bf16* W1F = (bf16*)w;  w += (size_t)NGRP * KEXP * D_IN * 2;
    bf16* W2F = (bf16*)w;  w += (size_t)NGRP * H_DIM * KEXP * 2;
    bf16* NF  = (bf16*)w;  w += (size_t)N_NODES * H_DIM * 2;
    float* EMB  = (float*)w; w += (size_t)F_SEG * H_DIM * 4;
    float* MEAN = (float*)w; w += (size_t)G_SEG * H_DIM * 4;
    float* RSIG = (float*)w; w += (size_t)G_SEG * H_DIM * 4;

    convert_weights<<<1280, 256, 0, stream>>>(W1, W2, W1F, W2F);
    mlp_kernel<<<2048, 512, 0, stream>>>(x, gidx, W1F, b1, W2F, b2, NF);
    pool_kernel<<<2048, 256, 0, stream>>>(NF, EMB);
    stats_kernel<<<dim3(32, 4), 128, 0, stream>>>(EMB, MEAN, RSIG);
    classifier_kernel<<<512, 256, 0, stream>>>(EMB, MEAN, RSIG, w_out, b_out, out);
}